// Round 17
// baseline (148.308 us; speedup 1.0000x reference)
//
#include <hip/hip_runtime.h>
#include <hip/hip_bf16.h>

// MDTA (multi-head cross attention with l2-normed q/k) for MI355X.
// B=8, N=4096, Ktok=256, C=512, H=8, D=64. Inputs f32, output f32.
//
// R8 187.9 -> R14 134.9 -> R15 129.6 -> R16 127.6.
// R17 (attn): fragment-contiguous LDS layout (each MFMA operand = contiguous
// 1KB -> zero read bank conflicts; permutation done on the global source of
// global_load_lds), and QBLK=128 (2 q-tiles per wave: K-fragment reads shared
// by 2 MFMAs, half the blocks, 2 softmax chains of ILP).
//
// Pipeline: cvt_all (W,X,S->bf16) -> proj_all -> attn_fused -> out_gemm.

typedef __bf16 bf16;
typedef __attribute__((ext_vector_type(8))) __bf16 bf16x8;
typedef __attribute__((ext_vector_type(4))) float f32x4;

#if __has_builtin(__builtin_amdgcn_exp2f)
#define EXP2(x) __builtin_amdgcn_exp2f(x)
#else
#define EXP2(x) exp2f(x)
#endif

__device__ __forceinline__ void gload_lds16(const void* g, void* l) {
  __builtin_amdgcn_global_load_lds(
      (__attribute__((address_space(1))) void*)g,
      (__attribute__((address_space(3))) void*)l, 16, 0, 0);
}

__device__ __forceinline__ unsigned pack2(float a, float b) {
  unsigned short x = __builtin_bit_cast(unsigned short, (bf16)a);
  unsigned short y = __builtin_bit_cast(unsigned short, (bf16)b);
  return (unsigned)x | ((unsigned)y << 16);
}

// ---------------------------------------------------------------------------
// Convert X (2097152 chunks), S (131072), Wq/Wk/Wv/Wo (32768 each) to bf16.
// ---------------------------------------------------------------------------
__global__ __launch_bounds__(256) void cvt_all(
    const float* __restrict__ X, const float* __restrict__ S,
    const float* __restrict__ Wq, const float* __restrict__ Wk,
    const float* __restrict__ Wv, const float* __restrict__ Wo,
    bf16* __restrict__ Xb, bf16* __restrict__ Sb, bf16* __restrict__ Wqb,
    bf16* __restrict__ Wkb, bf16* __restrict__ Wvb, bf16* __restrict__ Wob) {
  int i = blockIdx.x * 256 + threadIdx.x;
  const float* src;
  bf16* dst;
  int r;
  if (i < 2097152) {
    src = X; dst = Xb; r = i;
  } else if (i < 2228224) {
    src = S; dst = Sb; r = i - 2097152;
  } else {
    int j = i - 2228224;
    int w = j >> 15;
    r = j & 32767;
    src = (w == 0) ? Wq : (w == 1) ? Wk : (w == 2) ? Wv : Wo;
    dst = (w == 0) ? Wqb : (w == 1) ? Wkb : (w == 2) ? Wvb : Wob;
  }
  float4 a = *(const float4*)(src + (size_t)r * 8);
  float4 b = *(const float4*)(src + (size_t)r * 8 + 4);
  uint4 v;
  v.x = pack2(a.x, a.y);
  v.y = pack2(a.z, a.w);
  v.z = pack2(b.x, b.y);
  v.w = pack2(b.z, b.w);
  *(uint4*)(dst + (size_t)r * 8) = v;
}

// ---------------------------------------------------------------------------
// Fused Q/K/V projection, all-bf16. 128x128 tile, BK=32, 16 stages,
// depth-3 gload_lds pipeline. Epilogue: l2norm (Q additionally scaled by
// temp[h]*log2e for the attn exp2 path) -> swizzled LDS re-tile -> bf16x8.
// ---------------------------------------------------------------------------
__global__ __launch_bounds__(256) void proj_all(
    const bf16* __restrict__ Xb, const bf16* __restrict__ Sb,
    const bf16* __restrict__ Wqb, const bf16* __restrict__ Wkb,
    const bf16* __restrict__ Wvb, const float* __restrict__ temp,
    bf16* __restrict__ Q, bf16* __restrict__ Kn, bf16* __restrict__ Vt) {
  __shared__ __align__(16) char smem[49152];  // 3x(As 8KB + Bs 8KB)

  const int lg = (blockIdx.x & 7) * 144 + (blockIdx.x >> 3);

  const bf16* A;
  const bf16* W;
  int m0, kind;  // 0=Q, 1=K, 2=V
  if (lg < 1024) {
    kind = 0; A = Xb; W = Wqb; m0 = (lg >> 2) * 128;
  } else if (lg < 1088) {
    kind = 1; A = Sb; W = Wkb; m0 = ((lg - 1024) >> 2) * 128;
  } else {
    kind = 2; A = Sb; W = Wvb; m0 = ((lg - 1088) >> 2) * 128;
  }
  const int n0 = (lg & 3) * 128;

  const int tid = threadIdx.x;
  const int wid = tid >> 6, lane = tid & 63;
  const int wr = wid >> 1, wc = wid & 1;
  const int g = lane >> 4, c16 = lane & 15;
  const int r0 = tid >> 2, cc0 = tid & 3;
  const int r1 = (256 + tid) >> 2, cc1 = tid & 3;
  const int dst0 = (tid & ~63) * 16, dst1 = (256 + (tid & ~63)) * 16;

  f32x4 acc[4][4] = {};

#define PSTAGE(kb, buf)                                                     \
  {                                                                         \
    char* as = smem + (buf) * 8192;                                         \
    char* bs = smem + 24576 + (buf) * 8192;                                 \
    gload_lds16(A + (size_t)(m0 + r0) * 512 + (kb) + cc0 * 8, as + dst0);   \
    gload_lds16(A + (size_t)(m0 + r1) * 512 + (kb) + cc1 * 8, as + dst1);   \
    gload_lds16(W + (size_t)(n0 + r0) * 512 + (kb) + cc0 * 8, bs + dst0);   \
    gload_lds16(W + (size_t)(n0 + r1) * 512 + (kb) + cc1 * 8, bs + dst1);   \
  }

#define PCOMPUTE(buf)                                                       \
  {                                                                         \
    const bf16* as = (const bf16*)(smem + (buf) * 8192);                    \
    const bf16* bs = (const bf16*)(smem + 24576 + (buf) * 8192);            \
    bf16x8 af[4], bfr[4];                                                   \
    _Pragma("unroll") for (int mi = 0; mi < 4; ++mi) af[mi] =               \
        *(const bf16x8*)(as + (wr * 64 + mi * 16 + c16) * 32 + g * 8);      \
    _Pragma("unroll") for (int ni = 0; ni < 4; ++ni) bfr[ni] =              \
        *(const bf16x8*)(bs + (wc * 64 + ni * 16 + c16) * 32 + g * 8);      \
    _Pragma("unroll") for (int mi = 0; mi < 4; ++mi)                        \
        _Pragma("unroll") for (int ni = 0; ni < 4; ++ni) acc[mi][ni] =      \
            __builtin_amdgcn_mfma_f32_16x16x32_bf16(af[mi], bfr[ni],        \
                                                    acc[mi][ni], 0, 0, 0);  \
  }

  PSTAGE(0, 0);
  PSTAGE(32, 1);
  int bufc = 0;
  for (int t = 0; t < 14; ++t) {
    int bufn = bufc + 2;
    if (bufn >= 3) bufn -= 3;
    PSTAGE((t + 2) * 32, bufn);
    asm volatile("s_waitcnt vmcnt(8)" ::: "memory");
    __builtin_amdgcn_s_barrier();
    PCOMPUTE(bufc);
    __builtin_amdgcn_s_barrier();
    if (++bufc == 3) bufc = 0;
  }
  asm volatile("s_waitcnt vmcnt(4)" ::: "memory");
  __builtin_amdgcn_s_barrier();
  PCOMPUTE(bufc);
  __builtin_amdgcn_s_barrier();
  if (++bufc == 3) bufc = 0;
  asm volatile("s_waitcnt vmcnt(0)" ::: "memory");
  __builtin_amdgcn_s_barrier();
  PCOMPUTE(bufc);

  __syncthreads();  // release K-loop LDS for epilogue re-tile

  // ---- epilogue. C/D frag: col = lane&15, row = (lane>>4)*4 + j   [m89]
  if (kind != 2) {
    bf16* C = (kind == 0) ? Q : Kn;
    // Q additionally scaled by temp[h]*log2(e): attn uses exp2(s - max).
    const float sc =
        (kind == 0) ? temp[(n0 + wc * 64) >> 6] * 1.44269504088896f : 1.0f;
    char* eps = smem + wid * 8192;  // wave-private 64x64 bf16 tile
#pragma unroll
    for (int mi = 0; mi < 4; ++mi) {
      float ss[4];
#pragma unroll
      for (int j = 0; j < 4; ++j) {
        float s = 0.f;
#pragma unroll
        for (int ni = 0; ni < 4; ++ni) {
          float v = acc[mi][ni][j];
          s += v * v;
        }
        ss[j] = s;
      }
#pragma unroll
      for (int msk = 1; msk < 16; msk <<= 1)
#pragma unroll
        for (int j = 0; j < 4; ++j) ss[j] += __shfl_xor(ss[j], msk, 64);
      float inv[4];
#pragma unroll
      for (int j = 0; j < 4; ++j)
        inv[j] = rsqrtf(fmaxf(ss[j], 1e-24f)) * sc;
#pragma unroll
      for (int ni = 0; ni < 4; ++ni)
#pragma unroll
        for (int j = 0; j < 4; ++j) {
          int row = mi * 16 + g * 4 + j, col = ni * 16 + c16;
          int off = (row * 128 + col * 2) ^ ((row & 7) << 4);
          *(bf16*)(eps + off) = (bf16)(acc[mi][ni][j] * inv[j]);
        }
    }
    asm volatile("s_waitcnt lgkmcnt(0)" ::: "memory");
#pragma unroll
    for (int it = 0; it < 8; ++it) {
      int c = it * 64 + lane;
      int row = c >> 3, ch = c & 7;
      int off = (row * 128 + ch * 16) ^ ((row & 7) << 4);
      bf16x8 v = *(const bf16x8*)(eps + off);
      *(bf16x8*)(C + (size_t)(m0 + wr * 64 + row) * 512 + n0 + wc * 64 +
                 ch * 8) = v;
    }
  } else {
    // transposed store into Vt[b][h][d][t] (M=2048): 8B stores, small.
#pragma unroll
    for (int mi = 0; mi < 4; ++mi) {
      int m = m0 + wr * 64 + mi * 16 + g * 4;  // +j
      int b = m >> 8, tt = m & 255;
#pragma unroll
      for (int ni = 0; ni < 4; ++ni) {
        int col = n0 + wc * 64 + ni * 16 + c16;
        int h = col >> 6, d = col & 63;
        uint2 v;
        v.x = pack2(acc[mi][ni][0], acc[mi][ni][1]);
        v.y = pack2(acc[mi][ni][2], acc[mi][ni][3]);
        *(uint2*)(Vt + ((size_t)((b * 8 + h) * 64 + d) * 256 + tt)) = v;
      }
    }
  }
#undef PSTAGE
#undef PCOMPUTE
}

// ---------------------------------------------------------------------------
// out = X + O @ Wo^T, f32 output. Depth-3 pipeline + f32x4 re-tiled epilogue.
// ---------------------------------------------------------------------------
__global__ __launch_bounds__(256) void out_gemm(
    const bf16* __restrict__ O, const bf16* __restrict__ Wob,
    const float* __restrict__ Xres, float* __restrict__ out) {
  __shared__ __align__(16) char smem[49152];

  const int lg = (blockIdx.x & 7) * 128 + (blockIdx.x >> 3);  // XCD swizzle
  const int m0 = (lg >> 2) * 128, n0 = (lg & 3) * 128;

  const int tid = threadIdx.x;
  const int wid = tid >> 6, lane = tid & 63;
  const int wr = wid >> 1, wc = wid & 1;
  const int g = lane >> 4, c16 = lane & 15;
  const int r0 = tid >> 2, cc0 = tid & 3;
  const int r1 = (256 + tid) >> 2, cc1 = tid & 3;
  const int dst0 = (tid & ~63) * 16, dst1 = (256 + (tid & ~63)) * 16;

  f32x4 acc[4][4] = {};

#define OSTAGE(kb, buf)                                                      \
  {                                                                          \
    char* as = smem + (buf) * 8192;                                          \
    char* bs = smem + 24576 + (buf) * 8192;                                  \
    gload_lds16(O + (size_t)(m0 + r0) * 512 + (kb) + cc0 * 8, as + dst0);    \
    gload_lds16(O + (size_t)(m0 + r1) * 512 + (kb) + cc1 * 8, as + dst1);    \
    gload_lds16(Wob + (size_t)(n0 + r0) * 512 + (kb) + cc0 * 8, bs + dst0);  \
    gload_lds16(Wob + (size_t)(n0 + r1) * 512 + (kb) + cc1 * 8, bs + dst1);  \
  }

#define OCOMPUTE(buf)                                                       \
  {                                                                         \
    const bf16* as = (const bf16*)(smem + (buf) * 8192);                    \
    const bf16* bs = (const bf16*)(smem + 24576 + (buf) * 8192);            \
    bf16x8 af[4], bfr[4];                                                   \
    _Pragma("unroll") for (int mi = 0; mi < 4; ++mi) af[mi] =               \
        *(const bf16x8*)(as + (wr * 64 + mi * 16 + c16) * 32 + g * 8);      \
    _Pragma("unroll") for (int ni = 0; ni < 4; ++ni) bfr[ni] =              \
        *(const bf16x8*)(bs + (wc * 64 + ni * 16 + c16) * 32 + g * 8);      \
    _Pragma("unroll") for (int mi = 0; mi < 4; ++mi)                        \
        _Pragma("unroll") for (int ni = 0; ni < 4; ++ni) acc[mi][ni] =      \
            __builtin_amdgcn_mfma_f32_16x16x32_bf16(af[mi], bfr[ni],        \
                                                    acc[mi][ni], 0, 0, 0);  \
  }

  OSTAGE(0, 0);
  OSTAGE(32, 1);
  int bufc = 0;
  for (int t = 0; t < 14; ++t) {
    int bufn = bufc + 2;
    if (bufn >= 3) bufn -= 3;
    OSTAGE((t + 2) * 32, bufn);
    asm volatile("s_waitcnt vmcnt(8)" ::: "memory");
    __builtin_amdgcn_s_barrier();
    OCOMPUTE(bufc);
    __builtin_amdgcn_s_barrier();
    if (++bufc == 3) bufc = 0;
  }
  asm volatile("s_waitcnt vmcnt(4)" ::: "memory");
  __builtin_amdgcn_s_barrier();
  OCOMPUTE(bufc);
  __builtin_amdgcn_s_barrier();
  if (++bufc == 3) bufc = 0;
  asm volatile("s_waitcnt vmcnt(0)" ::: "memory");
  __builtin_amdgcn_s_barrier();
  OCOMPUTE(bufc);

  __syncthreads();  // release K-loop LDS for f32 re-tile

  // Epilogue: 2 passes x (32 rows x 64 cols f32) per wave, swizzled LDS,
  // then float4 X-load + add + float4 store (full-line writes).
  char* eps = smem + wid * 8192;
#pragma unroll
  for (int p = 0; p < 2; ++p) {
#pragma unroll
    for (int mm = 0; mm < 2; ++mm)
#pragma unroll
      for (int ni = 0; ni < 4; ++ni)
#pragma unroll
        for (int j = 0; j < 4; ++j) {
          int row = mm * 16 + g * 4 + j, col = ni * 16 + c16;
          int off = (row * 256 + col * 4) ^ ((row & 7) << 4);
          *(float*)(eps + off) = acc[p * 2 + mm][ni][j];
        }
    asm volatile("s_waitcnt lgkmcnt(0)" ::: "memory");
#pragma unroll
    for (int it = 0; it < 8; ++it) {
      int c = it * 64 + lane;
      int row = c >> 4, ch = c & 15;
      int off = (row * 256 + ch * 16) ^ ((row & 7) << 4);
      float4 v = *(const float4*)(eps + off);
      size_t gr = (size_t)(m0 + wr * 64 + p * 32 + row) * 512 + n0 +
                  wc * 64 + ch * 4;
      float4 x = *(const float4*)(Xres + gr);
      v.x += x.x;
      v.y += x.y;
      v.z += x.z;
      v.w += x.w;
      *(float4*)(out + gr) = v;
    }
    asm volatile("s_waitcnt lgkmcnt(0)" ::: "memory");
  }
#undef OSTAGE
#undef OCOMPUTE
}

// ---------------------------------------------------------------------------
// Fused attention. Block = (b, h, 128 q-rows), 256 thr = 4 waves, 64 KB LDS
// -> 2 blocks/CU. Wave w owns q rows {p*64 + w*16 .. +16} for p=0,1.
// FRAGMENT-CONTIGUOUS LDS: every MFMA operand block is a contiguous 1KB
// (16B unit index = instr*64 + c16*4 + g) -> conflict-free ds_read_b128.
// global_load_lds writes linearly; the per-lane GLOBAL address does the
// permutation. K fragments are shared by both q-tiles (2 MFMAs per read).
//   [0,32768)     K frags (32 instr x 1KB) -> dead after QK^T -> P slices
//                 (8KB per wave, fragment-contiguous, reused for p=0,1)
//   [32768,65536) V frags (32 instr x 1KB)
// Q pre-scaled by temp*log2e -> exp2 softmax, 1/sum deferred to oacc.
// ---------------------------------------------------------------------------
__global__ __launch_bounds__(256) void attn_fused(
    const bf16* __restrict__ Qn, const bf16* __restrict__ Kn,
    const bf16* __restrict__ Vt, bf16* __restrict__ O) {
  __shared__ __align__(16) char smem[65536];

  const int tid = threadIdx.x;
  const int w = tid >> 6, lane = tid & 63;
  const int g = lane >> 4, c16 = lane & 15;
  // XCD swizzle: 2048 = 8 XCDs x 256; blocks sharing (b,h) -> same XCD L2.
  const int lg = (blockIdx.x & 7) * 256 + (blockIdx.x >> 3);
  const int nt = lg & 31, h = (lg >> 5) & 7, b = lg >> 8;
  const int n0 = nt * 128;

  // ---- stage K,V via gload_lds; fragment-contiguous dest, permuted source.
  // chunk c (16B): instr = c>>6, r = c&63 -> fc16 = r>>2, fg = r&3.
  //   K instr = mi*2+s   -> K[mi*16+fc16][s*32 + fg*8 ..]
  //   V instr = ks*4+ni  -> V^T[ni*16+fc16][ks*32 + fg*8 ..]
  {
    const bf16* Ksrc = Kn + ((size_t)b * 256) * 512 + h * 64;
    const bf16* Vsrc = Vt + (size_t)((b * 8 + h) * 64) * 256;
#pragma unroll
    for (int it = 0; it < 8; ++it) {
      int base = it * 256 + w * 64;  // wave-uniform
      int c = base + lane;
      int ii = c >> 6, rr = c & 63;
      int fc16 = rr >> 2, fg = rr & 3;
      int kmi = ii >> 1, ks_ = ii & 1;
      gload_lds16(Ksrc + (size_t)(kmi * 16 + fc16) * 512 + ks_ * 32 + fg * 8,
                  smem + base * 16);
      int vks = ii >> 2, vni = ii & 3;
      gload_lds16(Vsrc + (size_t)(vni * 16 + fc16) * 256 + vks * 32 + fg * 8,
                  smem + 32768 + base * 16);
    }
  }
  // ---- Q fragments direct to registers (2 q-tiles)
  const bf16* Qsrc = Qn + ((size_t)b * 4096 + n0) * 512 + h * 64;
  bf16x8 qf0[2], qf1[2];
  {
    const bf16* q0 = Qsrc + (size_t)(w * 16 + c16) * 512;
    const bf16* q1 = Qsrc + (size_t)(64 + w * 16 + c16) * 512;
    qf0[0] = *(const bf16x8*)(q0 + g * 8);
    qf0[1] = *(const bf16x8*)(q0 + 32 + g * 8);
    qf1[0] = *(const bf16x8*)(q1 + g * 8);
    qf1[1] = *(const bf16x8*)(q1 + 32 + g * 8);
  }
  __syncthreads();  // drains gload_lds (vmcnt) + barrier

  // ---- QK^T for both tiles; kf shared (2 MFMAs per ds_read)
  f32x4 sacc0[16] = {}, sacc1[16] = {};
#pragma unroll
  for (int mi = 0; mi < 16; ++mi) {
#pragma unroll
    for (int s = 0; s < 2; ++s) {
      bf16x8 kf =
          *(const bf16x8*)(smem + ((mi * 2 + s) * 64 + c16 * 4 + g) * 16);
      sacc0[mi] = __builtin_amdgcn_mfma_f32_16x16x32_bf16(kf, qf0[s],
                                                          sacc0[mi], 0, 0, 0);
      sacc1[mi] = __builtin_amdgcn_mfma_f32_16x16x32_bf16(kf, qf1[s],
                                                          sacc1[mi], 0, 0, 0);
    }
  }

  // ---- softmax (two independent chains; temp*log2e pre-folded into Q)
  float mxa[4] = {-1e30f, -1e30f, -1e30f, -1e30f};
  float mxb[4] = {-1e30f, -1e30f, -1e30f, -1e30f};
#pragma unroll
  for (int mi = 0; mi < 16; ++mi)
#pragma unroll
    for (int j = 0; j < 4; ++j) {
      mxa[j] = fmaxf(mxa[j], sacc0[mi][j]);
      mxb[j] = fmaxf(mxb[j], sacc1[mi][j]);
    }
  float mx0 = fmaxf(fmaxf(mxa[0], mxa[1]), fmaxf(mxa[2], mxa[3]));
  float mx1 = fmaxf(fmaxf(mxb[0], mxb[1]), fmaxf(mxb[2], mxb[3]));
  mx0 = fmaxf(mx0, __shfl_xor(mx0, 16, 64));
  mx0 = fmaxf(mx0, __shfl_xor(mx0, 32, 64));
  mx1 = fmaxf(mx1, __shfl_xor(mx1, 16, 64));
  mx1 = fmaxf(mx1, __shfl_xor(mx1, 32, 64));
  float sa[4] = {0.f, 0.f, 0.f, 0.f}, sb[4] = {0.f, 0.f, 0.f, 0.f};
#pragma unroll
  for (int mi = 0; mi < 16; ++mi)
#pragma unroll
    for (int j = 0; j < 4; ++j) {
      float p0 = EXP2(sacc0[mi][j] - mx0);
      float p1 = EXP2(sacc1[mi][j] - mx1);
      sacc0[mi][j] = p0;
      sacc1[mi][j] = p1;
      sa[j] += p0;
      sb[j] += p1;
    }
  float sum0 = (sa[0] + sa[1]) + (sa[2] + sa[3]);
  float sum1 = (sb[0] + sb[1]) + (sb[2] + sb[3]);
  sum0 += __shfl_xor(sum0, 16, 64);
  sum0 += __shfl_xor(sum0, 32, 64);
  sum1 += __shfl_xor(sum1, 16, 64);
  sum1 += __shfl_xor(sum1, 32, 64);
  float inv0 = 1.0f / sum0, inv1 = 1.0f / sum1;

  __syncthreads();  // all K reads done; K region dead -> P slices

  char* pslice = smem + w * 8192;  // wave-private 8KB

  // P-write: lane holds P[q][k=mi*16+g*4+j] -> unit (mi>>1)*64 + c16*4 +
  // ((mi&1)*2 + (g>>1)), byte (g&1)*8. PA read (instr ks): unit ks*64 +
  // c16*4 + g -> contiguous 1KB, conflict-free.
#define DO_PV(SACC, INV, P)                                                  \
  {                                                                          \
    _Pragma("unroll") for (int mi = 0; mi < 16; ++mi) {                      \
      int cl = (mi >> 1) * 64 + c16 * 4 + ((mi & 1) * 2 + (g >> 1));         \
      uint2 v;                                                               \
      v.x = pack2(SACC[mi][0], SACC[mi][1]);                                 \
      v.y = pack2(SACC[mi][2], SACC[mi][3]);                                 \
      *(uint2*)(pslice + cl * 16 + (g & 1) * 8) = v;                         \
    }                                                                        \
    asm volatile("s_waitcnt lgkmcnt(0)" ::: "memory");                       \
    __builtin_amdgcn_sched_barrier(0);                                       \
    f32x4 oacc[4] = {};                                                      \
    _Pragma("unroll") for (int ks = 0; ks < 8; ++ks) {                       \
      bf16x8 pa =                                                            \
          *(const bf16x8*)(pslice + (ks * 64 + c16 * 4 + g) * 16);           \
      _Pragma("unroll") for (int ni = 0; ni < 4; ++ni) {                     \
        bf16x8 vb = *(const bf16x8*)(                                        \
            smem + 32768 + ((ks * 4 + ni) * 64 + c16 * 4 + g) * 16);         \
        oacc[ni] = __builtin_amdgcn_mfma_f32_16x16x32_bf16(pa, vb,           \
                                                           oacc[ni], 0,0,0); \
      }                                                                      \
    }                                                                        \
    asm volatile("s_waitcnt lgkmcnt(0)" ::: "memory");                       \
    __builtin_amdgcn_sched_barrier(0);                                       \
    _Pragma("unroll") for (int ni = 0; ni < 4; ++ni)                         \
        _Pragma("unroll") for (int j = 0; j < 4; ++j) {                      \
      int row = g * 4 + j, col = ni * 16 + c16;                              \
      int off = (row * 128 + col * 2) ^ ((row & 7) << 4);                    \
      *(bf16*)(pslice + off) = (bf16)(oacc[ni][j] * (INV));                  \
    }                                                                        \
    asm volatile("s_waitcnt lgkmcnt(0)" ::: "memory");                       \
    __builtin_amdgcn_sched_barrier(0);                                       \
    _Pragma("unroll") for (int it = 0; it < 2; ++it) {                       \
      int c = it * 64 + lane;                                                \
      int row = c >> 3, ch = c & 7;                                          \
      int off = (row * 128 + ch * 16) ^ ((row & 7) << 4);                    \
      bf16x8 v = *(const bf16x8*)(pslice + off);                             \
      *(bf16x8*)(O + ((size_t)b * 4096 + n0 + (P) * 64 + w * 16 + row) *     \
                         512 + h * 64 + ch * 8) = v;                         \
    }                                                                        \
    asm volatile("s_waitcnt lgkmcnt(0)" ::: "memory");                       \
    __builtin_amdgcn_sched_barrier(0);                                       \
  }

  DO_PV(sacc0, inv0, 0);
  DO_PV(sacc1, inv1, 1);
#undef DO_PV
}

// ---------------------------------------------------------------------------
extern "C" void kernel_launch(void* const* d_in, const int* in_sizes, int n_in,
                              void* d_out, int out_size, void* d_ws,
                              size_t ws_size, hipStream_t stream) {
  const float* X = (const float*)d_in[0];
  const float* S = (const float*)d_in[1];
  const float* Wq = (const float*)d_in[2];
  const float* Wk = (const float*)d_in[3];
  const float* Wv = (const float*)d_in[4];
  const float* Wo = (const float*)d_in[5];
  const float* temp = (const float*)d_in[6];
  float* out = (float*)d_out;

  char* ws = (char*)d_ws;
  bf16* Qws = (bf16*)ws;                      // 32768*512*2 = 33,554,432 B
  bf16* Kws = (bf16*)(ws + 33554432);         //  2048*512*2 =  2,097,152 B
  bf16* Vtws = (bf16*)(ws + 35651584);        //  8*8*64*256*2 = 2,097,152 B
  bf16* Wqb = (bf16*)(ws + 37748736);         //  512*512*2 = 524,288 B each
  bf16* Wkb = (bf16*)(ws + 38273024);
  bf16* Wvb = (bf16*)(ws + 38797312);
  bf16* Wob = (bf16*)(ws + 39321600);

  // Xb/Sb scratch inside d_out (67.1 MB f32): dead before out_gemm writes.
  bf16* Xb = (bf16*)d_out;                      // 33,554,432 B
  bf16* Sb = (bf16*)((char*)d_out + 33554432);  //  2,097,152 B

  cvt_all<<<dim3(9216), dim3(256), 0, stream>>>(X, S, Wq, Wk, Wv, Wo, Xb, Sb,
                                                Wqb, Wkb, Wvb, Wob);
  proj_all<<<dim3(1152), dim3(256), 0, stream>>>(Xb, Sb, Wqb, Wkb, Wvb, temp,
                                                 Qws, Kws, Vtws);
  attn_fused<<<dim3(2048), dim3(256), 0, stream>>>(Qws, Kws, Vtws, Qws);
  out_gemm<<<dim3(1024), dim3(256), 0, stream>>>(Qws, Wob, X, out);
}

// Round 18
// 131.792 us; speedup vs baseline: 1.1253x; 1.1253x over previous
//
#include <hip/hip_runtime.h>
#include <hip/hip_bf16.h>

// MDTA (multi-head cross attention with l2-normed q/k) for MI355X.
// B=8, N=4096, Ktok=256, C=512, H=8, D=64. Inputs f32, output f32.
//
// R8 187.9 -> R14 134.9 -> R15 129.6 -> R16 127.6 -> R17 148.3 (REGRESSION:
// wrong unit composition c16*4+g = 64B lane stride = 8-way conflict, 11M;
// + QBLK=128 doubled VGPR to 160).
// R18: revert attn to R16 structure; ONLY change = lane-contiguous fragment
// layout (unit = instr*64 + lane) for K/V/P -> truly conflict-free ds_read.
//
// Pipeline: cvt_all (W,X,S->bf16) -> proj_all -> attn_fused -> out_gemm.

typedef __bf16 bf16;
typedef __attribute__((ext_vector_type(8))) __bf16 bf16x8;
typedef __attribute__((ext_vector_type(4))) float f32x4;

#if __has_builtin(__builtin_amdgcn_exp2f)
#define EXP2(x) __builtin_amdgcn_exp2f(x)
#else
#define EXP2(x) exp2f(x)
#endif

__device__ __forceinline__ void gload_lds16(const void* g, void* l) {
  __builtin_amdgcn_global_load_lds(
      (__attribute__((address_space(1))) void*)g,
      (__attribute__((address_space(3))) void*)l, 16, 0, 0);
}

__device__ __forceinline__ unsigned pack2(float a, float b) {
  unsigned short x = __builtin_bit_cast(unsigned short, (bf16)a);
  unsigned short y = __builtin_bit_cast(unsigned short, (bf16)b);
  return (unsigned)x | ((unsigned)y << 16);
}

// ---------------------------------------------------------------------------
// Convert X (2097152 chunks), S (131072), Wq/Wk/Wv/Wo (32768 each) to bf16.
// ---------------------------------------------------------------------------
__global__ __launch_bounds__(256) void cvt_all(
    const float* __restrict__ X, const float* __restrict__ S,
    const float* __restrict__ Wq, const float* __restrict__ Wk,
    const float* __restrict__ Wv, const float* __restrict__ Wo,
    bf16* __restrict__ Xb, bf16* __restrict__ Sb, bf16* __restrict__ Wqb,
    bf16* __restrict__ Wkb, bf16* __restrict__ Wvb, bf16* __restrict__ Wob) {
  int i = blockIdx.x * 256 + threadIdx.x;
  const float* src;
  bf16* dst;
  int r;
  if (i < 2097152) {
    src = X; dst = Xb; r = i;
  } else if (i < 2228224) {
    src = S; dst = Sb; r = i - 2097152;
  } else {
    int j = i - 2228224;
    int w = j >> 15;
    r = j & 32767;
    src = (w == 0) ? Wq : (w == 1) ? Wk : (w == 2) ? Wv : Wo;
    dst = (w == 0) ? Wqb : (w == 1) ? Wkb : (w == 2) ? Wvb : Wob;
  }
  float4 a = *(const float4*)(src + (size_t)r * 8);
  float4 b = *(const float4*)(src + (size_t)r * 8 + 4);
  uint4 v;
  v.x = pack2(a.x, a.y);
  v.y = pack2(a.z, a.w);
  v.z = pack2(b.x, b.y);
  v.w = pack2(b.z, b.w);
  *(uint4*)(dst + (size_t)r * 8) = v;
}

// ---------------------------------------------------------------------------
// Fused Q/K/V projection, all-bf16. 128x128 tile, BK=32, 16 stages,
// depth-3 gload_lds pipeline. Epilogue: l2norm (Q additionally scaled by
// temp[h]*log2e for the attn exp2 path) -> swizzled LDS re-tile -> bf16x8.
// ---------------------------------------------------------------------------
__global__ __launch_bounds__(256) void proj_all(
    const bf16* __restrict__ Xb, const bf16* __restrict__ Sb,
    const bf16* __restrict__ Wqb, const bf16* __restrict__ Wkb,
    const bf16* __restrict__ Wvb, const float* __restrict__ temp,
    bf16* __restrict__ Q, bf16* __restrict__ Kn, bf16* __restrict__ Vt) {
  __shared__ __align__(16) char smem[49152];  // 3x(As 8KB + Bs 8KB)

  const int lg = (blockIdx.x & 7) * 144 + (blockIdx.x >> 3);

  const bf16* A;
  const bf16* W;
  int m0, kind;  // 0=Q, 1=K, 2=V
  if (lg < 1024) {
    kind = 0; A = Xb; W = Wqb; m0 = (lg >> 2) * 128;
  } else if (lg < 1088) {
    kind = 1; A = Sb; W = Wkb; m0 = ((lg - 1024) >> 2) * 128;
  } else {
    kind = 2; A = Sb; W = Wvb; m0 = ((lg - 1088) >> 2) * 128;
  }
  const int n0 = (lg & 3) * 128;

  const int tid = threadIdx.x;
  const int wid = tid >> 6, lane = tid & 63;
  const int wr = wid >> 1, wc = wid & 1;
  const int g = lane >> 4, c16 = lane & 15;
  const int r0 = tid >> 2, cc0 = tid & 3;
  const int r1 = (256 + tid) >> 2, cc1 = tid & 3;
  const int dst0 = (tid & ~63) * 16, dst1 = (256 + (tid & ~63)) * 16;

  f32x4 acc[4][4] = {};

#define PSTAGE(kb, buf)                                                     \
  {                                                                         \
    char* as = smem + (buf) * 8192;                                         \
    char* bs = smem + 24576 + (buf) * 8192;                                 \
    gload_lds16(A + (size_t)(m0 + r0) * 512 + (kb) + cc0 * 8, as + dst0);   \
    gload_lds16(A + (size_t)(m0 + r1) * 512 + (kb) + cc1 * 8, as + dst1);   \
    gload_lds16(W + (size_t)(n0 + r0) * 512 + (kb) + cc0 * 8, bs + dst0);   \
    gload_lds16(W + (size_t)(n0 + r1) * 512 + (kb) + cc1 * 8, bs + dst1);   \
  }

#define PCOMPUTE(buf)                                                       \
  {                                                                         \
    const bf16* as = (const bf16*)(smem + (buf) * 8192);                    \
    const bf16* bs = (const bf16*)(smem + 24576 + (buf) * 8192);            \
    bf16x8 af[4], bfr[4];                                                   \
    _Pragma("unroll") for (int mi = 0; mi < 4; ++mi) af[mi] =               \
        *(const bf16x8*)(as + (wr * 64 + mi * 16 + c16) * 32 + g * 8);      \
    _Pragma("unroll") for (int ni = 0; ni < 4; ++ni) bfr[ni] =              \
        *(const bf16x8*)(bs + (wc * 64 + ni * 16 + c16) * 32 + g * 8);      \
    _Pragma("unroll") for (int mi = 0; mi < 4; ++mi)                        \
        _Pragma("unroll") for (int ni = 0; ni < 4; ++ni) acc[mi][ni] =      \
            __builtin_amdgcn_mfma_f32_16x16x32_bf16(af[mi], bfr[ni],        \
                                                    acc[mi][ni], 0, 0, 0);  \
  }

  PSTAGE(0, 0);
  PSTAGE(32, 1);
  int bufc = 0;
  for (int t = 0; t < 14; ++t) {
    int bufn = bufc + 2;
    if (bufn >= 3) bufn -= 3;
    PSTAGE((t + 2) * 32, bufn);
    asm volatile("s_waitcnt vmcnt(8)" ::: "memory");
    __builtin_amdgcn_s_barrier();
    PCOMPUTE(bufc);
    __builtin_amdgcn_s_barrier();
    if (++bufc == 3) bufc = 0;
  }
  asm volatile("s_waitcnt vmcnt(4)" ::: "memory");
  __builtin_amdgcn_s_barrier();
  PCOMPUTE(bufc);
  __builtin_amdgcn_s_barrier();
  if (++bufc == 3) bufc = 0;
  asm volatile("s_waitcnt vmcnt(0)" ::: "memory");
  __builtin_amdgcn_s_barrier();
  PCOMPUTE(bufc);

  __syncthreads();  // release K-loop LDS for epilogue re-tile

  // ---- epilogue. C/D frag: col = lane&15, row = (lane>>4)*4 + j   [m89]
  if (kind != 2) {
    bf16* C = (kind == 0) ? Q : Kn;
    // Q additionally scaled by temp[h]*log2(e): attn uses exp2(s - max).
    const float sc =
        (kind == 0) ? temp[(n0 + wc * 64) >> 6] * 1.44269504088896f : 1.0f;
    char* eps = smem + wid * 8192;  // wave-private 64x64 bf16 tile
#pragma unroll
    for (int mi = 0; mi < 4; ++mi) {
      float ss[4];
#pragma unroll
      for (int j = 0; j < 4; ++j) {
        float s = 0.f;
#pragma unroll
        for (int ni = 0; ni < 4; ++ni) {
          float v = acc[mi][ni][j];
          s += v * v;
        }
        ss[j] = s;
      }
#pragma unroll
      for (int msk = 1; msk < 16; msk <<= 1)
#pragma unroll
        for (int j = 0; j < 4; ++j) ss[j] += __shfl_xor(ss[j], msk, 64);
      float inv[4];
#pragma unroll
      for (int j = 0; j < 4; ++j)
        inv[j] = rsqrtf(fmaxf(ss[j], 1e-24f)) * sc;
#pragma unroll
      for (int ni = 0; ni < 4; ++ni)
#pragma unroll
        for (int j = 0; j < 4; ++j) {
          int row = mi * 16 + g * 4 + j, col = ni * 16 + c16;
          int off = (row * 128 + col * 2) ^ ((row & 7) << 4);
          *(bf16*)(eps + off) = (bf16)(acc[mi][ni][j] * inv[j]);
        }
    }
    asm volatile("s_waitcnt lgkmcnt(0)" ::: "memory");
#pragma unroll
    for (int it = 0; it < 8; ++it) {
      int c = it * 64 + lane;
      int row = c >> 3, ch = c & 7;
      int off = (row * 128 + ch * 16) ^ ((row & 7) << 4);
      bf16x8 v = *(const bf16x8*)(eps + off);
      *(bf16x8*)(C + (size_t)(m0 + wr * 64 + row) * 512 + n0 + wc * 64 +
                 ch * 8) = v;
    }
  } else {
    // transposed store into Vt[b][h][d][t] (M=2048): 8B stores, small.
#pragma unroll
    for (int mi = 0; mi < 4; ++mi) {
      int m = m0 + wr * 64 + mi * 16 + g * 4;  // +j
      int b = m >> 8, tt = m & 255;
#pragma unroll
      for (int ni = 0; ni < 4; ++ni) {
        int col = n0 + wc * 64 + ni * 16 + c16;
        int h = col >> 6, d = col & 63;
        uint2 v;
        v.x = pack2(acc[mi][ni][0], acc[mi][ni][1]);
        v.y = pack2(acc[mi][ni][2], acc[mi][ni][3]);
        *(uint2*)(Vt + ((size_t)((b * 8 + h) * 64 + d) * 256 + tt)) = v;
      }
    }
  }
#undef PSTAGE
#undef PCOMPUTE
}

// ---------------------------------------------------------------------------
// out = X + O @ Wo^T, f32 output. Depth-3 pipeline + f32x4 re-tiled epilogue.
// ---------------------------------------------------------------------------
__global__ __launch_bounds__(256) void out_gemm(
    const bf16* __restrict__ O, const bf16* __restrict__ Wob,
    const float* __restrict__ Xres, float* __restrict__ out) {
  __shared__ __align__(16) char smem[49152];

  const int lg = (blockIdx.x & 7) * 128 + (blockIdx.x >> 3);  // XCD swizzle
  const int m0 = (lg >> 2) * 128, n0 = (lg & 3) * 128;

  const int tid = threadIdx.x;
  const int wid = tid >> 6, lane = tid & 63;
  const int wr = wid >> 1, wc = wid & 1;
  const int g = lane >> 4, c16 = lane & 15;
  const int r0 = tid >> 2, cc0 = tid & 3;
  const int r1 = (256 + tid) >> 2, cc1 = tid & 3;
  const int dst0 = (tid & ~63) * 16, dst1 = (256 + (tid & ~63)) * 16;

  f32x4 acc[4][4] = {};

#define OSTAGE(kb, buf)                                                      \
  {                                                                          \
    char* as = smem + (buf) * 8192;                                          \
    char* bs = smem + 24576 + (buf) * 8192;                                  \
    gload_lds16(O + (size_t)(m0 + r0) * 512 + (kb) + cc0 * 8, as + dst0);    \
    gload_lds16(O + (size_t)(m0 + r1) * 512 + (kb) + cc1 * 8, as + dst1);    \
    gload_lds16(Wob + (size_t)(n0 + r0) * 512 + (kb) + cc0 * 8, bs + dst0);  \
    gload_lds16(Wob + (size_t)(n0 + r1) * 512 + (kb) + cc1 * 8, bs + dst1);  \
  }

#define OCOMPUTE(buf)                                                       \
  {                                                                         \
    const bf16* as = (const bf16*)(smem + (buf) * 8192);                    \
    const bf16* bs = (const bf16*)(smem + 24576 + (buf) * 8192);            \
    bf16x8 af[4], bfr[4];                                                   \
    _Pragma("unroll") for (int mi = 0; mi < 4; ++mi) af[mi] =               \
        *(const bf16x8*)(as + (wr * 64 + mi * 16 + c16) * 32 + g * 8);      \
    _Pragma("unroll") for (int ni = 0; ni < 4; ++ni) bfr[ni] =              \
        *(const bf16x8*)(bs + (wc * 64 + ni * 16 + c16) * 32 + g * 8);      \
    _Pragma("unroll") for (int mi = 0; mi < 4; ++mi)                        \
        _Pragma("unroll") for (int ni = 0; ni < 4; ++ni) acc[mi][ni] =      \
            __builtin_amdgcn_mfma_f32_16x16x32_bf16(af[mi], bfr[ni],        \
                                                    acc[mi][ni], 0, 0, 0);  \
  }

  OSTAGE(0, 0);
  OSTAGE(32, 1);
  int bufc = 0;
  for (int t = 0; t < 14; ++t) {
    int bufn = bufc + 2;
    if (bufn >= 3) bufn -= 3;
    OSTAGE((t + 2) * 32, bufn);
    asm volatile("s_waitcnt vmcnt(8)" ::: "memory");
    __builtin_amdgcn_s_barrier();
    OCOMPUTE(bufc);
    __builtin_amdgcn_s_barrier();
    if (++bufc == 3) bufc = 0;
  }
  asm volatile("s_waitcnt vmcnt(4)" ::: "memory");
  __builtin_amdgcn_s_barrier();
  OCOMPUTE(bufc);
  __builtin_amdgcn_s_barrier();
  if (++bufc == 3) bufc = 0;
  asm volatile("s_waitcnt vmcnt(0)" ::: "memory");
  __builtin_amdgcn_s_barrier();
  OCOMPUTE(bufc);

  __syncthreads();  // release K-loop LDS for f32 re-tile

  // Epilogue: 2 passes x (32 rows x 64 cols f32) per wave, swizzled LDS,
  // then float4 X-load + add + float4 store (full-line writes).
  char* eps = smem + wid * 8192;
#pragma unroll
  for (int p = 0; p < 2; ++p) {
#pragma unroll
    for (int mm = 0; mm < 2; ++mm)
#pragma unroll
      for (int ni = 0; ni < 4; ++ni)
#pragma unroll
        for (int j = 0; j < 4; ++j) {
          int row = mm * 16 + g * 4 + j, col = ni * 16 + c16;
          int off = (row * 256 + col * 4) ^ ((row & 7) << 4);
          *(float*)(eps + off) = acc[p * 2 + mm][ni][j];
        }
    asm volatile("s_waitcnt lgkmcnt(0)" ::: "memory");
#pragma unroll
    for (int it = 0; it < 8; ++it) {
      int c = it * 64 + lane;
      int row = c >> 4, ch = c & 15;
      int off = (row * 256 + ch * 16) ^ ((row & 7) << 4);
      float4 v = *(const float4*)(eps + off);
      size_t gr = (size_t)(m0 + wr * 64 + p * 32 + row) * 512 + n0 +
                  wc * 64 + ch * 4;
      float4 x = *(const float4*)(Xres + gr);
      v.x += x.x;
      v.y += x.y;
      v.z += x.z;
      v.w += x.w;
      *(float4*)(out + gr) = v;
    }
    asm volatile("s_waitcnt lgkmcnt(0)" ::: "memory");
  }
#undef OSTAGE
#undef OCOMPUTE
}

// ---------------------------------------------------------------------------
// Fused attention (R16 structure + corrected lane-contiguous fragments).
// Block = (b, h, 64 q-rows), 256 thr = 4 waves, 64 KB LDS -> 2 blocks/CU.
// LDS layout: 16B unit index = instr*64 + lane  (lane = g*16 + c16), so each
// ds_read_b128 has per-lane stride 16B -> conflict-free. Staged linearly by
// global_load_lds with the permutation applied to the GLOBAL source address.
//   [0,32768)     K frags (32 instr) -> dead after QK^T -> P slices (8KB/wave)
//   [32768,65536) V frags (32 instr)
// Q direct-to-reg; Q pre-scaled by temp*log2e -> exp2 softmax, 1/sum deferred.
// ---------------------------------------------------------------------------
__global__ __launch_bounds__(256) void attn_fused(
    const bf16* __restrict__ Qn, const bf16* __restrict__ Kn,
    const bf16* __restrict__ Vt, bf16* __restrict__ O) {
  __shared__ __align__(16) char smem[65536];

  const int tid = threadIdx.x;
  const int w = tid >> 6, lane = tid & 63;
  const int g = lane >> 4, c16 = lane & 15;
  // XCD swizzle: 4096 = 8 XCDs x 512; blocks sharing (b,h) -> same XCD L2.
  const int lg = (blockIdx.x & 7) * 512 + (blockIdx.x >> 3);
  const int nt = lg & 63, h = (lg >> 6) & 7, b = lg >> 9;
  const int n0 = nt * 64;

  // ---- stage K,V: chunk c -> instr = c>>6, rr = c&63; fc16 = rr&15,
  //      fg = rr>>4. Unit holds row (x*16+fc16), k-slice (y*32 + fg*8).
  //   K instr = mi*2+s  -> K[mi*16+fc16][s*32 + fg*8]
  //   V instr = ks*4+ni -> V^T[ni*16+fc16][ks*32 + fg*8]
  {
    const bf16* Ksrc = Kn + ((size_t)b * 256) * 512 + h * 64;
    const bf16* Vsrc = Vt + (size_t)((b * 8 + h) * 64) * 256;
#pragma unroll
    for (int it = 0; it < 8; ++it) {
      int base = it * 256 + w * 64;  // wave-uniform
      int c = base + lane;
      int ii = c >> 6, rr = c & 63;
      int fc16 = rr & 15, fg = rr >> 4;
      int kmi = ii >> 1, ks_ = ii & 1;
      gload_lds16(Ksrc + (size_t)(kmi * 16 + fc16) * 512 + ks_ * 32 + fg * 8,
                  smem + base * 16);
      int vks = ii >> 2, vni = ii & 3;
      gload_lds16(Vsrc + (size_t)(vni * 16 + fc16) * 256 + vks * 32 + fg * 8,
                  smem + 32768 + base * 16);
    }
  }
  // ---- Q fragments direct to registers
  const int q = w * 16 + c16;  // this lane's q row (0..63)
  const bf16* Qsrc = Qn + ((size_t)b * 4096 + n0) * 512 + h * 64;
  bf16x8 qf[2];
  qf[0] = *(const bf16x8*)(Qsrc + (size_t)q * 512 + g * 8);
  qf[1] = *(const bf16x8*)(Qsrc + (size_t)q * 512 + 32 + g * 8);
  __syncthreads();  // drains gload_lds (vmcnt) + barrier

  // ---- S^T = mfma(K, Q^T): lane holds P[q][k], k = mi*16 + g*4 + j
  f32x4 sacc[16] = {};
#pragma unroll
  for (int mi = 0; mi < 16; ++mi) {
#pragma unroll
    for (int s = 0; s < 2; ++s) {
      bf16x8 kf = *(const bf16x8*)(smem + ((mi * 2 + s) * 64 + lane) * 16);
      sacc[mi] = __builtin_amdgcn_mfma_f32_16x16x32_bf16(kf, qf[s], sacc[mi],
                                                         0, 0, 0);
    }
  }

  // ---- softmax over k (temp*log2e pre-folded into Q)
  float mx4[4] = {-1e30f, -1e30f, -1e30f, -1e30f};
#pragma unroll
  for (int mi = 0; mi < 16; ++mi)
#pragma unroll
    for (int j = 0; j < 4; ++j) mx4[j] = fmaxf(mx4[j], sacc[mi][j]);
  float mx = fmaxf(fmaxf(mx4[0], mx4[1]), fmaxf(mx4[2], mx4[3]));
  mx = fmaxf(mx, __shfl_xor(mx, 16, 64));
  mx = fmaxf(mx, __shfl_xor(mx, 32, 64));
  float sm4[4] = {0.f, 0.f, 0.f, 0.f};
#pragma unroll
  for (int mi = 0; mi < 16; ++mi)
#pragma unroll
    for (int j = 0; j < 4; ++j) {
      float p = EXP2(sacc[mi][j] - mx);
      sacc[mi][j] = p;
      sm4[j] += p;
    }
  float sum = (sm4[0] + sm4[1]) + (sm4[2] + sm4[3]);
  sum += __shfl_xor(sum, 16, 64);
  sum += __shfl_xor(sum, 32, 64);
  float inv = 1.0f / sum;

  __syncthreads();  // all K reads done; K region dead -> P slices

  // ---- P -> wave-private slice, fragment layout.
  // lane holds P[q][k0 = mi*16 + g*4] (4 bf16 = 8B). Destination:
  // unit = (mi>>1)*64 + ((mi&1)*2 + (g>>1))*16 + c16, byte (g&1)*8.
  // PA read (instr ks): unit = ks*64 + lane -> conflict-free.
  char* pslice = smem + w * 8192;
#pragma unroll
  for (int mi = 0; mi < 16; ++mi) {
    int un = (mi >> 1) * 64 + ((mi & 1) * 2 + (g >> 1)) * 16 + c16;
    uint2 v;
    v.x = pack2(sacc[mi][0], sacc[mi][1]);
    v.y = pack2(sacc[mi][2], sacc[mi][3]);
    *(uint2*)(pslice + un * 16 + (g & 1) * 8) = v;
  }
  asm volatile("s_waitcnt lgkmcnt(0)" ::: "memory");
  __builtin_amdgcn_sched_barrier(0);

  // ---- O = P @ V (wave-private P; V fragments lane-contiguous)
  f32x4 oacc[4] = {};
#pragma unroll
  for (int ks = 0; ks < 8; ++ks) {
    bf16x8 pa = *(const bf16x8*)(pslice + (ks * 64 + lane) * 16);
#pragma unroll
    for (int ni = 0; ni < 4; ++ni) {
      bf16x8 vb =
          *(const bf16x8*)(smem + 32768 + ((ks * 4 + ni) * 64 + lane) * 16);
      oacc[ni] = __builtin_amdgcn_mfma_f32_16x16x32_bf16(pa, vb, oacc[ni],
                                                         0, 0, 0);
    }
  }
  asm volatile("s_waitcnt lgkmcnt(0)" ::: "memory");
  __builtin_amdgcn_sched_barrier(0);

  // ---- normalize (deferred 1/sum) + O re-tile in own wave's dead P slice
  {
#pragma unroll
    for (int ni = 0; ni < 4; ++ni)
#pragma unroll
      for (int j = 0; j < 4; ++j) {
        int row = g * 4 + j, col = ni * 16 + c16;
        int off = (row * 128 + col * 2) ^ ((row & 7) << 4);
        *(bf16*)(pslice + off) = (bf16)(oacc[ni][j] * inv);
      }
    asm volatile("s_waitcnt lgkmcnt(0)" ::: "memory");
    __builtin_amdgcn_sched_barrier(0);
#pragma unroll
    for (int it = 0; it < 2; ++it) {
      int c = it * 64 + lane;
      int row = c >> 3, ch = c & 7;
      int off = (row * 128 + ch * 16) ^ ((row & 7) << 4);
      bf16x8 v = *(const bf16x8*)(pslice + off);
      *(bf16x8*)(O + ((size_t)b * 4096 + n0 + w * 16 + row) * 512 + h * 64 +
                 ch * 8) = v;
    }
  }
}

// ---------------------------------------------------------------------------
extern "C" void kernel_launch(void* const* d_in, const int* in_sizes, int n_in,
                              void* d_out, int out_size, void* d_ws,
                              size_t ws_size, hipStream_t stream) {
  const float* X = (const float*)d_in[0];
  const float* S = (const float*)d_in[1];
  const float* Wq = (const float*)d_in[2];
  const float* Wk = (const float*)d_in[3];
  const float* Wv = (const float*)d_in[4];
  const float* Wo = (const float*)d_in[5];
  const float* temp = (const float*)d_in[6];
  float* out = (float*)d_out;

  char* ws = (char*)d_ws;
  bf16* Qws = (bf16*)ws;                      // 32768*512*2 = 33,554,432 B
  bf16* Kws = (bf16*)(ws + 33554432);         //  2048*512*2 =  2,097,152 B
  bf16* Vtws = (bf16*)(ws + 35651584);        //  8*8*64*256*2 = 2,097,152 B
  bf16* Wqb = (bf16*)(ws + 37748736);         //  512*512*2 = 524,288 B each
  bf16* Wkb = (bf16*)(ws + 38273024);
  bf16* Wvb = (bf16*)(ws + 38797312);
  bf16* Wob = (bf16*)(ws + 39321600);

  // Xb/Sb scratch inside d_out (67.1 MB f32): dead before out_gemm writes.
  bf16* Xb = (bf16*)d_out;                      // 33,554,432 B
  bf16* Sb = (bf16*)((char*)d_out + 33554432);  //  2,097,152 B

  cvt_all<<<dim3(9216), dim3(256), 0, stream>>>(X, S, Wq, Wk, Wv, Wo, Xb, Sb,
                                                Wqb, Wkb, Wvb, Wob);
  proj_all<<<dim3(1152), dim3(256), 0, stream>>>(Xb, Sb, Wqb, Wkb, Wvb, temp,
                                                 Qws, Kws, Vtws);
  attn_fused<<<dim3(4096), dim3(256), 0, stream>>>(Qws, Kws, Vtws, Qws);
  out_gemm<<<dim3(1024), dim3(256), 0, stream>>>(Qws, Wob, X, out);
}

// Round 19
// 127.724 us; speedup vs baseline: 1.1612x; 1.0319x over previous
//
#include <hip/hip_runtime.h>
#include <hip/hip_bf16.h>

// MDTA (multi-head cross attention with l2-normed q/k) for MI355X.
// B=8, N=4096, Ktok=256, C=512, H=8, D=64. Inputs f32, output f32.
//
// R8 187.9 -> R14 134.9 -> R15 129.6 -> R16 127.6 -> R17 148.3 -> R18 131.8.
// R18 lesson: lane-contiguous LDS fixed read conflicts (3.67M->1.05M) but
// scattered the staging's GLOBAL source -> slower. R19: producer-side fix --
// proj writes Q/K/V directly in MFMA-fragment image order, so attn staging
// is a purely LINEAR global_load_lds (coalesced, conflict-free) and Q loads
// are coalesced. attn O -> ws (no aliasing); Qfrag overlaps dead Sb in d_out
// (proj split into KV-phase then Q-phase launches to serialize).
//
// Pipeline: cvt_all -> proj<KV> -> proj<Q> -> attn_fused -> out_gemm.

typedef __bf16 bf16;
typedef __attribute__((ext_vector_type(8))) __bf16 bf16x8;
typedef __attribute__((ext_vector_type(4))) float f32x4;

#if __has_builtin(__builtin_amdgcn_exp2f)
#define EXP2(x) __builtin_amdgcn_exp2f(x)
#else
#define EXP2(x) exp2f(x)
#endif

__device__ __forceinline__ void gload_lds16(const void* g, void* l) {
  __builtin_amdgcn_global_load_lds(
      (__attribute__((address_space(1))) void*)g,
      (__attribute__((address_space(3))) void*)l, 16, 0, 0);
}

__device__ __forceinline__ unsigned pack2(float a, float b) {
  unsigned short x = __builtin_bit_cast(unsigned short, (bf16)a);
  unsigned short y = __builtin_bit_cast(unsigned short, (bf16)b);
  return (unsigned)x | ((unsigned)y << 16);
}

// ---------------------------------------------------------------------------
// Convert X (2097152 chunks), S (131072), Wq/Wk/Wv/Wo (32768 each) to bf16.
// ---------------------------------------------------------------------------
__global__ __launch_bounds__(256) void cvt_all(
    const float* __restrict__ X, const float* __restrict__ S,
    const float* __restrict__ Wq, const float* __restrict__ Wk,
    const float* __restrict__ Wv, const float* __restrict__ Wo,
    bf16* __restrict__ Xb, bf16* __restrict__ Sb, bf16* __restrict__ Wqb,
    bf16* __restrict__ Wkb, bf16* __restrict__ Wvb, bf16* __restrict__ Wob) {
  int i = blockIdx.x * 256 + threadIdx.x;
  const float* src;
  bf16* dst;
  int r;
  if (i < 2097152) {
    src = X; dst = Xb; r = i;
  } else if (i < 2228224) {
    src = S; dst = Sb; r = i - 2097152;
  } else {
    int j = i - 2228224;
    int w = j >> 15;
    r = j & 32767;
    src = (w == 0) ? Wq : (w == 1) ? Wk : (w == 2) ? Wv : Wo;
    dst = (w == 0) ? Wqb : (w == 1) ? Wkb : (w == 2) ? Wvb : Wob;
  }
  float4 a = *(const float4*)(src + (size_t)r * 8);
  float4 b = *(const float4*)(src + (size_t)r * 8 + 4);
  uint4 v;
  v.x = pack2(a.x, a.y);
  v.y = pack2(a.z, a.w);
  v.z = pack2(b.x, b.y);
  v.w = pack2(b.z, b.w);
  *(uint4*)(dst + (size_t)r * 8) = v;
}

// ---------------------------------------------------------------------------
// Projections. 128x128 tile, BK=32, 16 stages, depth-3 gload_lds pipeline.
// PHASE 0 (grid 1024): Q = l2norm(X@Wq^T)*temp*log2e -> Qfrag images.
// PHASE 1 (grid 128):  Kn = l2norm(S@Wk^T) -> Kfrag; V = S@Wv^T -> Vfrag.
// Fragment image per (b,h): 16B unit u = instr*64 + lane holds
//   Q/K: row (x*16 + lane&15), d-slice (s*32 + (lane>>4)*8), instr = x*2+s
//   V:   V^T row d = ni*16 + (lane&15), t-slice (ks*32 + (lane>>4)*8),
//        instr = ks*4 + ni
// ---------------------------------------------------------------------------
template <int PHASE>
__global__ __launch_bounds__(256) void proj_all(
    const bf16* __restrict__ Xb, const bf16* __restrict__ Sb,
    const bf16* __restrict__ Wqb, const bf16* __restrict__ Wkb,
    const bf16* __restrict__ Wvb, const float* __restrict__ temp,
    bf16* __restrict__ Qf, bf16* __restrict__ Kf, bf16* __restrict__ Vf) {
  __shared__ __align__(16) char smem[49152];  // 3x(As 8KB + Bs 8KB)

  const bf16* A;
  const bf16* W;
  int m0, n0, kind;
  if (PHASE == 0) {
    const int lg = (blockIdx.x & 7) * 128 + (blockIdx.x >> 3);  // 1024
    kind = 0; A = Xb; W = Wqb;
    m0 = (lg >> 2) * 128;
    n0 = (lg & 3) * 128;
  } else {
    const int lg = (blockIdx.x & 7) * 16 + (blockIdx.x >> 3);  // 128
    if (lg < 64) {
      kind = 1; A = Sb; W = Wkb;
      m0 = (lg >> 2) * 128;
      n0 = (lg & 3) * 128;
    } else {
      kind = 2; A = Sb; W = Wvb;
      m0 = ((lg - 64) >> 2) * 128;
      n0 = ((lg - 64) & 3) * 128;
    }
  }

  const int tid = threadIdx.x;
  const int wid = tid >> 6, lane = tid & 63;
  const int wr = wid >> 1, wc = wid & 1;
  const int g = lane >> 4, c16 = lane & 15;
  const int r0 = tid >> 2, cc0 = tid & 3;
  const int r1 = (256 + tid) >> 2, cc1 = tid & 3;
  const int dst0 = (tid & ~63) * 16, dst1 = (256 + (tid & ~63)) * 16;

  f32x4 acc[4][4] = {};

#define PSTAGE(kb, buf)                                                     \
  {                                                                         \
    char* as = smem + (buf) * 8192;                                         \
    char* bs = smem + 24576 + (buf) * 8192;                                 \
    gload_lds16(A + (size_t)(m0 + r0) * 512 + (kb) + cc0 * 8, as + dst0);   \
    gload_lds16(A + (size_t)(m0 + r1) * 512 + (kb) + cc1 * 8, as + dst1);   \
    gload_lds16(W + (size_t)(n0 + r0) * 512 + (kb) + cc0 * 8, bs + dst0);   \
    gload_lds16(W + (size_t)(n0 + r1) * 512 + (kb) + cc1 * 8, bs + dst1);   \
  }

#define PCOMPUTE(buf)                                                       \
  {                                                                         \
    const bf16* as = (const bf16*)(smem + (buf) * 8192);                    \
    const bf16* bs = (const bf16*)(smem + 24576 + (buf) * 8192);            \
    bf16x8 af[4], bfr[4];                                                   \
    _Pragma("unroll") for (int mi = 0; mi < 4; ++mi) af[mi] =               \
        *(const bf16x8*)(as + (wr * 64 + mi * 16 + c16) * 32 + g * 8);      \
    _Pragma("unroll") for (int ni = 0; ni < 4; ++ni) bfr[ni] =              \
        *(const bf16x8*)(bs + (wc * 64 + ni * 16 + c16) * 32 + g * 8);      \
    _Pragma("unroll") for (int mi = 0; mi < 4; ++mi)                        \
        _Pragma("unroll") for (int ni = 0; ni < 4; ++ni) acc[mi][ni] =      \
            __builtin_amdgcn_mfma_f32_16x16x32_bf16(af[mi], bfr[ni],        \
                                                    acc[mi][ni], 0, 0, 0);  \
  }

  PSTAGE(0, 0);
  PSTAGE(32, 1);
  int bufc = 0;
  for (int t = 0; t < 14; ++t) {
    int bufn = bufc + 2;
    if (bufn >= 3) bufn -= 3;
    PSTAGE((t + 2) * 32, bufn);
    asm volatile("s_waitcnt vmcnt(8)" ::: "memory");
    __builtin_amdgcn_s_barrier();
    PCOMPUTE(bufc);
    __builtin_amdgcn_s_barrier();
    if (++bufc == 3) bufc = 0;
  }
  asm volatile("s_waitcnt vmcnt(4)" ::: "memory");
  __builtin_amdgcn_s_barrier();
  PCOMPUTE(bufc);
  __builtin_amdgcn_s_barrier();
  if (++bufc == 3) bufc = 0;
  asm volatile("s_waitcnt vmcnt(0)" ::: "memory");
  __builtin_amdgcn_s_barrier();
  PCOMPUTE(bufc);

  __syncthreads();  // release K-loop LDS for epilogue re-tile

  // ---- epilogue. C/D frag: col = lane&15, row = (lane>>4)*4 + j   [m89]
  if (kind != 2) {
    // l2norm (Q also scaled by temp[h]*log2e) -> LDS re-tile -> fragment img
    const float sc =
        (kind == 0) ? temp[(n0 + wc * 64) >> 6] * 1.44269504088896f : 1.0f;
    char* eps = smem + wid * 8192;  // wave-private 64x64 bf16 tile
#pragma unroll
    for (int mi = 0; mi < 4; ++mi) {
      float ss[4];
#pragma unroll
      for (int j = 0; j < 4; ++j) {
        float s = 0.f;
#pragma unroll
        for (int ni = 0; ni < 4; ++ni) {
          float v = acc[mi][ni][j];
          s += v * v;
        }
        ss[j] = s;
      }
#pragma unroll
      for (int msk = 1; msk < 16; msk <<= 1)
#pragma unroll
        for (int j = 0; j < 4; ++j) ss[j] += __shfl_xor(ss[j], msk, 64);
      float inv[4];
#pragma unroll
      for (int j = 0; j < 4; ++j)
        inv[j] = rsqrtf(fmaxf(ss[j], 1e-24f)) * sc;
#pragma unroll
      for (int ni = 0; ni < 4; ++ni)
#pragma unroll
        for (int j = 0; j < 4; ++j) {
          int row = mi * 16 + g * 4 + j, col = ni * 16 + c16;
          int off = (row * 128 + col * 2) ^ ((row & 7) << 4);
          *(bf16*)(eps + off) = (bf16)(acc[mi][ni][j] * inv[j]);
        }
    }
    asm volatile("s_waitcnt lgkmcnt(0)" ::: "memory");
    __builtin_amdgcn_sched_barrier(0);
#pragma unroll
    for (int it = 0; it < 8; ++it) {
      int c = it * 64 + lane;
      int row = c >> 3, ch = c & 7;
      int off = (row * 128 + ch * 16) ^ ((row & 7) << 4);
      bf16x8 v = *(const bf16x8*)(eps + off);
      int rg = m0 + wr * 64 + row;
      int cg = n0 + wc * 64 + ch * 8;
      int hh = cg >> 6, d0 = cg & 63;
      if (kind == 0) {
        int bb = rg >> 12, qr = rg & 4095;
        int unit = ((qr >> 4) * 2 + (d0 >> 5)) * 64 + ((d0 & 31) >> 3) * 16 +
                   (qr & 15);
        *(bf16x8*)(Qf + (((size_t)(bb * 8 + hh)) << 18) + unit * 8) = v;
      } else {
        int bb = rg >> 8, tt = rg & 255;
        int unit = ((tt >> 4) * 2 + (d0 >> 5)) * 64 + ((d0 & 31) >> 3) * 16 +
                   (tt & 15);
        *(bf16x8*)(Kf + (((size_t)(bb * 8 + hh)) << 14) + unit * 8) = v;
      }
    }
  } else {
    // V fragment store: 4 consecutive tokens at one (h,d) -> 8B into unit
#pragma unroll
    for (int mi = 0; mi < 4; ++mi) {
      int m = m0 + wr * 64 + mi * 16 + g * 4;  // +j
      int bb = m >> 8, tt = m & 255;
#pragma unroll
      for (int ni = 0; ni < 4; ++ni) {
        int col = n0 + wc * 64 + ni * 16 + c16;
        int hh = col >> 6, d = col & 63;
        int unit = ((tt >> 5) * 4 + (d >> 4)) * 64 + ((tt >> 3) & 3) * 16 +
                   (d & 15);
        uint2 v;
        v.x = pack2(acc[mi][ni][0], acc[mi][ni][1]);
        v.y = pack2(acc[mi][ni][2], acc[mi][ni][3]);
        *(uint2*)(Vf + (((size_t)(bb * 8 + hh)) << 14) + unit * 8 +
                  (tt & 7)) = v;
      }
    }
  }
#undef PSTAGE
#undef PCOMPUTE
}

// ---------------------------------------------------------------------------
// out = X + O @ Wo^T, f32 output. Depth-3 pipeline + f32x4 re-tiled epilogue.
// ---------------------------------------------------------------------------
__global__ __launch_bounds__(256) void out_gemm(
    const bf16* __restrict__ O, const bf16* __restrict__ Wob,
    const float* __restrict__ Xres, float* __restrict__ out) {
  __shared__ __align__(16) char smem[49152];

  const int lg = (blockIdx.x & 7) * 128 + (blockIdx.x >> 3);  // XCD swizzle
  const int m0 = (lg >> 2) * 128, n0 = (lg & 3) * 128;

  const int tid = threadIdx.x;
  const int wid = tid >> 6, lane = tid & 63;
  const int wr = wid >> 1, wc = wid & 1;
  const int g = lane >> 4, c16 = lane & 15;
  const int r0 = tid >> 2, cc0 = tid & 3;
  const int r1 = (256 + tid) >> 2, cc1 = tid & 3;
  const int dst0 = (tid & ~63) * 16, dst1 = (256 + (tid & ~63)) * 16;

  f32x4 acc[4][4] = {};

#define OSTAGE(kb, buf)                                                      \
  {                                                                          \
    char* as = smem + (buf) * 8192;                                          \
    char* bs = smem + 24576 + (buf) * 8192;                                  \
    gload_lds16(O + (size_t)(m0 + r0) * 512 + (kb) + cc0 * 8, as + dst0);    \
    gload_lds16(O + (size_t)(m0 + r1) * 512 + (kb) + cc1 * 8, as + dst1);    \
    gload_lds16(Wob + (size_t)(n0 + r0) * 512 + (kb) + cc0 * 8, bs + dst0);  \
    gload_lds16(Wob + (size_t)(n0 + r1) * 512 + (kb) + cc1 * 8, bs + dst1);  \
  }

#define OCOMPUTE(buf)                                                       \
  {                                                                         \
    const bf16* as = (const bf16*)(smem + (buf) * 8192);                    \
    const bf16* bs = (const bf16*)(smem + 24576 + (buf) * 8192);            \
    bf16x8 af[4], bfr[4];                                                   \
    _Pragma("unroll") for (int mi = 0; mi < 4; ++mi) af[mi] =               \
        *(const bf16x8*)(as + (wr * 64 + mi * 16 + c16) * 32 + g * 8);      \
    _Pragma("unroll") for (int ni = 0; ni < 4; ++ni) bfr[ni] =              \
        *(const bf16x8*)(bs + (wc * 64 + ni * 16 + c16) * 32 + g * 8);      \
    _Pragma("unroll") for (int mi = 0; mi < 4; ++mi)                        \
        _Pragma("unroll") for (int ni = 0; ni < 4; ++ni) acc[mi][ni] =      \
            __builtin_amdgcn_mfma_f32_16x16x32_bf16(af[mi], bfr[ni],        \
                                                    acc[mi][ni], 0, 0, 0);  \
  }

  OSTAGE(0, 0);
  OSTAGE(32, 1);
  int bufc = 0;
  for (int t = 0; t < 14; ++t) {
    int bufn = bufc + 2;
    if (bufn >= 3) bufn -= 3;
    OSTAGE((t + 2) * 32, bufn);
    asm volatile("s_waitcnt vmcnt(8)" ::: "memory");
    __builtin_amdgcn_s_barrier();
    OCOMPUTE(bufc);
    __builtin_amdgcn_s_barrier();
    if (++bufc == 3) bufc = 0;
  }
  asm volatile("s_waitcnt vmcnt(4)" ::: "memory");
  __builtin_amdgcn_s_barrier();
  OCOMPUTE(bufc);
  __builtin_amdgcn_s_barrier();
  if (++bufc == 3) bufc = 0;
  asm volatile("s_waitcnt vmcnt(0)" ::: "memory");
  __builtin_amdgcn_s_barrier();
  OCOMPUTE(bufc);

  __syncthreads();  // release K-loop LDS for f32 re-tile

  // Epilogue: 2 passes x (32 rows x 64 cols f32) per wave, swizzled LDS,
  // then float4 X-load + add + float4 store (full-line writes).
  char* eps = smem + wid * 8192;
#pragma unroll
  for (int p = 0; p < 2; ++p) {
#pragma unroll
    for (int mm = 0; mm < 2; ++mm)
#pragma unroll
      for (int ni = 0; ni < 4; ++ni)
#pragma unroll
        for (int j = 0; j < 4; ++j) {
          int row = mm * 16 + g * 4 + j, col = ni * 16 + c16;
          int off = (row * 256 + col * 4) ^ ((row & 7) << 4);
          *(float*)(eps + off) = acc[p * 2 + mm][ni][j];
        }
    asm volatile("s_waitcnt lgkmcnt(0)" ::: "memory");
    __builtin_amdgcn_sched_barrier(0);
#pragma unroll
    for (int it = 0; it < 8; ++it) {
      int c = it * 64 + lane;
      int row = c >> 4, ch = c & 15;
      int off = (row * 256 + ch * 16) ^ ((row & 7) << 4);
      float4 v = *(const float4*)(eps + off);
      size_t gr = (size_t)(m0 + wr * 64 + p * 32 + row) * 512 + n0 +
                  wc * 64 + ch * 4;
      float4 x = *(const float4*)(Xres + gr);
      v.x += x.x;
      v.y += x.y;
      v.z += x.z;
      v.w += x.w;
      *(float4*)(out + gr) = v;
    }
    asm volatile("s_waitcnt lgkmcnt(0)" ::: "memory");
    __builtin_amdgcn_sched_barrier(0);
  }
#undef OSTAGE
#undef OCOMPUTE
}

// ---------------------------------------------------------------------------
// Fused attention. Block = (b, h, 64 q-rows), 256 thr = 4 waves, 64 KB LDS
// -> 2 blocks/CU. K/V/Q all pre-arranged in fragment image order, so staging
// is LINEAR gload_lds (coalesced) and every ds_read_b128 is lane-contiguous
// (conflict-free). Q direct-to-reg (coalesced). O -> ws (no aliasing).
//   [0,32768)     K frags (32 instr) -> dead after QK^T -> P slices (8KB/wave)
//   [32768,65536) V frags (32 instr)
// Q pre-scaled by temp*log2e -> exp2 softmax, 1/sum deferred to oacc.
// ---------------------------------------------------------------------------
__global__ __launch_bounds__(256) void attn_fused(
    const bf16* __restrict__ Qf, const bf16* __restrict__ Kf,
    const bf16* __restrict__ Vf, bf16* __restrict__ O) {
  __shared__ __align__(16) char smem[65536];

  const int tid = threadIdx.x;
  const int w = tid >> 6, lane = tid & 63;
  const int g = lane >> 4, c16 = lane & 15;
  // XCD swizzle: 4096 = 8 XCDs x 512; blocks sharing (b,h) -> same XCD L2.
  const int lg = (blockIdx.x & 7) * 512 + (blockIdx.x >> 3);
  const int nt = lg & 63, h = (lg >> 6) & 7, b = lg >> 9;
  const int n0 = nt * 64;

  const bf16* Kimg = Kf + (((size_t)(b * 8 + h)) << 14);
  const bf16* Vimg = Vf + (((size_t)(b * 8 + h)) << 14);
  const bf16* Qimg = Qf + (((size_t)(b * 8 + h)) << 18);

  // ---- stage K, V: purely linear (fragment images match LDS layout)
#pragma unroll
  for (int it = 0; it < 8; ++it) {
    int base = it * 256 + w * 64;  // wave-uniform 16B-unit base
    gload_lds16(Kimg + (size_t)(base + lane) * 8, smem + base * 16);
    gload_lds16(Vimg + (size_t)(base + lane) * 8, smem + 32768 + base * 16);
  }
  // ---- Q fragments direct to registers (coalesced: consecutive lanes ->
  // consecutive 16B within the image)
  bf16x8 qf[2];
  {
    int ub = (nt * 4 + w) * 2;
    qf[0] = *(const bf16x8*)(Qimg + (size_t)((ub + 0) * 64 + lane) * 8);
    qf[1] = *(const bf16x8*)(Qimg + (size_t)((ub + 1) * 64 + lane) * 8);
  }
  __syncthreads();  // drains gload_lds (vmcnt) + barrier

  // ---- S^T = mfma(K, Q^T): lane holds P[q][k], k = mi*16 + g*4 + j
  f32x4 sacc[16] = {};
#pragma unroll
  for (int mi = 0; mi < 16; ++mi) {
#pragma unroll
    for (int s = 0; s < 2; ++s) {
      bf16x8 kf = *(const bf16x8*)(smem + ((mi * 2 + s) * 64 + lane) * 16);
      sacc[mi] = __builtin_amdgcn_mfma_f32_16x16x32_bf16(kf, qf[s], sacc[mi],
                                                         0, 0, 0);
    }
  }

  // ---- softmax over k (temp*log2e pre-folded into Q)
  float mx4[4] = {-1e30f, -1e30f, -1e30f, -1e30f};
#pragma unroll
  for (int mi = 0; mi < 16; ++mi)
#pragma unroll
    for (int j = 0; j < 4; ++j) mx4[j] = fmaxf(mx4[j], sacc[mi][j]);
  float mx = fmaxf(fmaxf(mx4[0], mx4[1]), fmaxf(mx4[2], mx4[3]));
  mx = fmaxf(mx, __shfl_xor(mx, 16, 64));
  mx = fmaxf(mx, __shfl_xor(mx, 32, 64));
  float sm4[4] = {0.f, 0.f, 0.f, 0.f};
#pragma unroll
  for (int mi = 0; mi < 16; ++mi)
#pragma unroll
    for (int j = 0; j < 4; ++j) {
      float p = EXP2(sacc[mi][j] - mx);
      sacc[mi][j] = p;
      sm4[j] += p;
    }
  float sum = (sm4[0] + sm4[1]) + (sm4[2] + sm4[3]);
  sum += __shfl_xor(sum, 16, 64);
  sum += __shfl_xor(sum, 32, 64);
  float inv = 1.0f / sum;

  const int q = w * 16 + c16;  // this lane's q row (0..63)
  __syncthreads();  // all K reads done; K region dead -> P slices

  // ---- P -> wave-private slice, fragment layout:
  // unit = (mi>>1)*64 + ((mi&1)*2 + (g>>1))*16 + c16, byte (g&1)*8.
  char* pslice = smem + w * 8192;
#pragma unroll
  for (int mi = 0; mi < 16; ++mi) {
    int un = (mi >> 1) * 64 + ((mi & 1) * 2 + (g >> 1)) * 16 + c16;
    uint2 v;
    v.x = pack2(sacc[mi][0], sacc[mi][1]);
    v.y = pack2(sacc[mi][2], sacc[mi][3]);
    *(uint2*)(pslice + un * 16 + (g & 1) * 8) = v;
  }
  asm volatile("s_waitcnt lgkmcnt(0)" ::: "memory");
  __builtin_amdgcn_sched_barrier(0);

  // ---- O = P @ V (wave-private P; V fragments lane-contiguous)
  f32x4 oacc[4] = {};
#pragma unroll
  for (int ks = 0; ks < 8; ++ks) {
    bf16x8 pa = *(const bf16x8*)(pslice + (ks * 64 + lane) * 16);
#pragma unroll
    for (int ni = 0; ni < 4; ++ni) {
      bf16x8 vb =
          *(const bf16x8*)(smem + 32768 + ((ks * 4 + ni) * 64 + lane) * 16);
      oacc[ni] = __builtin_amdgcn_mfma_f32_16x16x32_bf16(pa, vb, oacc[ni],
                                                         0, 0, 0);
    }
  }
  asm volatile("s_waitcnt lgkmcnt(0)" ::: "memory");
  __builtin_amdgcn_sched_barrier(0);

  // ---- normalize (deferred 1/sum) + O re-tile in own wave's dead P slice
  {
#pragma unroll
    for (int ni = 0; ni < 4; ++ni)
#pragma unroll
      for (int j = 0; j < 4; ++j) {
        int row = g * 4 + j, col = ni * 16 + c16;
        int off = (row * 128 + col * 2) ^ ((row & 7) << 4);
        *(bf16*)(pslice + off) = (bf16)(oacc[ni][j] * inv);
      }
    asm volatile("s_waitcnt lgkmcnt(0)" ::: "memory");
    __builtin_amdgcn_sched_barrier(0);
#pragma unroll
    for (int it = 0; it < 2; ++it) {
      int c = it * 64 + lane;
      int row = c >> 3, ch = c & 7;
      int off = (row * 128 + ch * 16) ^ ((row & 7) << 4);
      bf16x8 v = *(const bf16x8*)(pslice + off);
      *(bf16x8*)(O + ((size_t)b * 4096 + n0 + w * 16 + row) * 512 + h * 64 +
                 ch * 8) = v;
    }
  }
}

// ---------------------------------------------------------------------------
extern "C" void kernel_launch(void* const* d_in, const int* in_sizes, int n_in,
                              void* d_out, int out_size, void* d_ws,
                              size_t ws_size, hipStream_t stream) {
  const float* X = (const float*)d_in[0];
  const float* S = (const float*)d_in[1];
  const float* Wq = (const float*)d_in[2];
  const float* Wk = (const float*)d_in[3];
  const float* Wv = (const float*)d_in[4];
  const float* Wo = (const float*)d_in[5];
  const float* temp = (const float*)d_in[6];
  float* out = (float*)d_out;

  char* ws = (char*)d_ws;
  bf16* Ows = (bf16*)ws;                      // 32768*512*2 = 33,554,432 B
  bf16* Kf = (bf16*)(ws + 33554432);          // 64 imgs * 32KB = 2,097,152 B
  bf16* Vf = (bf16*)(ws + 35651584);          // 2,097,152 B
  bf16* Wqb = (bf16*)(ws + 37748736);         // 512*512*2 = 524,288 B each
  bf16* Wkb = (bf16*)(ws + 38273024);
  bf16* Wvb = (bf16*)(ws + 38797312);
  bf16* Wob = (bf16*)(ws + 39321600);

  // d_out scratch (67.1 MB f32), all dead before out_gemm writes:
  //   Xb 32MB @0; Sb 2MB @32M; Qf 32MB @32M (overlaps Sb -- written by the
  //   Q-phase AFTER the KV-phase consumed Sb; kernel boundary serializes).
  bf16* Xb = (bf16*)d_out;                      // 33,554,432 B
  bf16* Sb = (bf16*)((char*)d_out + 33554432);  //  2,097,152 B
  bf16* Qf = (bf16*)((char*)d_out + 33554432);  // 33,554,432 B (ends 67.1MB)

  cvt_all<<<dim3(9216), dim3(256), 0, stream>>>(X, S, Wq, Wk, Wv, Wo, Xb, Sb,
                                                Wqb, Wkb, Wvb, Wob);
  proj_all<1><<<dim3(128), dim3(256), 0, stream>>>(Xb, Sb, Wqb, Wkb, Wvb,
                                                   temp, Qf, Kf, Vf);
  proj_all<0><<<dim3(1024), dim3(256), 0, stream>>>(Xb, Sb, Wqb, Wkb, Wvb,
                                                    temp, Qf, Kf, Vf);
  attn_fused<<<dim3(4096), dim3(256), 0, stream>>>(Qf, Kf, Vf, Ows);
  out_gemm<<<dim3(1024), dim3(256), 0, stream>>>(Ows, Wob, X, out);
}